// Round 3
// baseline (463.058 us; speedup 1.0000x reference)
//
#include <hip/hip_runtime.h>

// SpMM: out[b,m] = bias[m] + sum_{e: dst[e]==m} values[e] * x[b, src[e]]
// B=32, N=M=50000, E=1600000.
// v4: same two-phase bucket binning as v3 (write traffic solved: 6.25MB out,
// ~20MB sv), but k_accum restructured for latency hiding. Round-2 post-mortem:
// 347us at 2.3% HBM / 3.8% VALU / 37% occ = concurrency-starved dependent
// chain (uniform sv load -> xt gather -> LDS atomic, only 2 in flight/wave,
// 12 waves/CU). Fix: 1024-thread blocks (32 waves/CU), LDS-stage the sv
// segment with coalesced block-wide loads (kills the sv->xt chain), 32 slots
// x unroll-4 = ~64 independent 128B gathers in flight per block.

#define BATCH 32
#define DPB   64              // dsts per bucket -> NB = 782
#define ACC_TPB 1024
#define ACC_TILE 2560         // sv entries staged per round (20KB); P(bucket>2560) ~ 0
#define BIN_TPB 1024
#define BIN_EPT 4             // chunk = 4096 edges

// ---- transpose x (B,N) -> xt (N,B), LDS tiled ----
__global__ void k_transpose_x(const float* __restrict__ x, float* __restrict__ xt, int N) {
    __shared__ float tile[32][33];
    const int n0 = blockIdx.x * 32;
    const int tx = threadIdx.x;   // 0..31
    const int ty = threadIdx.y;   // 0..7
    #pragma unroll
    for (int k = 0; k < 4; ++k) {
        const int b = ty + 8 * k;
        const int n = n0 + tx;
        tile[tx][b] = (n < N) ? x[(size_t)b * N + n] : 0.0f;
    }
    __syncthreads();
    #pragma unroll
    for (int k = 0; k < 4; ++k) {
        const int n = n0 + ty + 8 * k;
        if (n < N) xt[(size_t)n * BATCH + tx] = tile[ty + 8 * k][tx];
    }
}

__global__ void k_zero_i32(int* __restrict__ p, int n) {
    const int i = blockIdx.x * blockDim.x + threadIdx.x;
    if (i < n) p[i] = 0;
}

// ---- per-bucket global histogram via LDS staging ----
__global__ __launch_bounds__(256) void k_bucket_count(const int* __restrict__ idx,
                                                      int* __restrict__ gcount,
                                                      int E, int NB) {
    extern __shared__ int hist[];
    for (int i = threadIdx.x; i < NB; i += blockDim.x) hist[i] = 0;
    __syncthreads();
    const int stride = gridDim.x * blockDim.x;
    for (int e = blockIdx.x * blockDim.x + threadIdx.x; e < E; e += stride) {
        atomicAdd(&hist[idx[E + e] / DPB], 1);
    }
    __syncthreads();
    for (int i = threadIdx.x; i < NB; i += blockDim.x) {
        if (hist[i]) atomicAdd(&gcount[i], hist[i]);
    }
}

// ---- single-wg exclusive scan of bucket counts (NB <= 1024) ----
__global__ __launch_bounds__(1024) void k_scan_buckets(const int* __restrict__ gcount,
                                                       int* __restrict__ bucket_base,
                                                       int* __restrict__ gcursor,
                                                       int NB, int E) {
    __shared__ int s[1024];
    const int tid = threadIdx.x;
    const int v = (tid < NB) ? gcount[tid] : 0;
    s[tid] = v;
    __syncthreads();
    for (int off = 1; off < 1024; off <<= 1) {
        const int t = (tid >= off) ? s[tid - off] : 0;
        __syncthreads();
        s[tid] += t;
        __syncthreads();
    }
    if (tid < NB) {
        const int excl = s[tid] - v;
        bucket_base[tid] = excl;
        gcursor[tid] = excl;
    }
    if (tid == 0) bucket_base[NB] = E;
}

// ---- bin edges into bucket-contiguous segments, packed (src|dl<<16, val) ----
__global__ __launch_bounds__(BIN_TPB) void k_bin(const int* __restrict__ idx,
                                                 const float* __restrict__ values,
                                                 int* __restrict__ gcursor,
                                                 int2* __restrict__ sv,
                                                 int E, int NB) {
    extern __shared__ int lds[];
    int* hist = lds;          // [NB] counts, then reused as local cursor
    int* base = lds + NB;     // [NB] this chunk's global segment base
    for (int i = threadIdx.x; i < NB; i += BIN_TPB) hist[i] = 0;
    __syncthreads();

    const int c0 = blockIdx.x * (BIN_TPB * BIN_EPT);
    int d[BIN_EPT];
    #pragma unroll
    for (int i = 0; i < BIN_EPT; ++i) {
        const int e = c0 + threadIdx.x + i * BIN_TPB;
        d[i] = (e < E) ? idx[E + e] : -1;
        if (d[i] >= 0) atomicAdd(&hist[d[i] / DPB], 1);
    }
    __syncthreads();
    // reserve contiguous global segments, reset local cursors
    for (int i = threadIdx.x; i < NB; i += BIN_TPB) {
        const int c = hist[i];
        base[i] = c ? atomicAdd(&gcursor[i], c) : 0;
        hist[i] = 0;
    }
    __syncthreads();
    #pragma unroll
    for (int i = 0; i < BIN_EPT; ++i) {
        if (d[i] >= 0) {
            const int e = c0 + threadIdx.x + i * BIN_TPB;
            const int bkt = d[i] / DPB;
            const int off = atomicAdd(&hist[bkt], 1);
            const int packed = (idx[e] & 0xFFFF) | ((d[i] % DPB) << 16);
            sv[base[bkt] + off] = make_int2(packed, __float_as_int(values[e]));
        }
    }
}

// ---- one block per bucket: LDS-staged sv + deep-MLP gather + LDS accumulate ----
__global__ __launch_bounds__(ACC_TPB) void k_accum(const int2* __restrict__ sv,
                                                   const int* __restrict__ bucket_base,
                                                   const float* __restrict__ xt,
                                                   const float* __restrict__ bias,
                                                   float* __restrict__ out, int M) {
    __shared__ float acc[DPB * 33];      // [dl][b] padded: bank = (dl+b)%32
    __shared__ int2  stage[ACC_TILE];    // staged sv segment
    for (int i = threadIdx.x; i < DPB * 33; i += ACC_TPB) acc[i] = 0.0f;

    const int bkt = blockIdx.x;
    const int beg = bucket_base[bkt];
    const int end = bucket_base[bkt + 1];

    const int slot  = threadIdx.x >> 5;      // 0..31 (half-wave id)
    const int lb    = threadIdx.x & 31;      // batch lane
    const int NSLOT = ACC_TPB / 32;          // 32

    for (int t0 = beg; t0 < end; t0 += ACC_TILE) {
        const int cnt = min(ACC_TILE, end - t0);
        __syncthreads();   // acc init done (1st iter) / prev tile consumed
        for (int i = threadIdx.x; i < cnt; i += ACC_TPB) stage[i] = sv[t0 + i];
        __syncthreads();
        int i = slot;
        for (; i + 3 * NSLOT < cnt; i += 4 * NSLOT) {
            const int2 a = stage[i];
            const int2 b2 = stage[i + NSLOT];
            const int2 c = stage[i + 2 * NSLOT];
            const int2 d = stage[i + 3 * NSLOT];
            const float xa = xt[(size_t)(a.x & 0xFFFF) * BATCH + lb];
            const float xb = xt[(size_t)(b2.x & 0xFFFF) * BATCH + lb];
            const float xc = xt[(size_t)(c.x & 0xFFFF) * BATCH + lb];
            const float xd = xt[(size_t)(d.x & 0xFFFF) * BATCH + lb];
            atomicAdd(&acc[((a.x >> 16) & 63) * 33 + lb], __int_as_float(a.y) * xa);
            atomicAdd(&acc[((b2.x >> 16) & 63) * 33 + lb], __int_as_float(b2.y) * xb);
            atomicAdd(&acc[((c.x >> 16) & 63) * 33 + lb], __int_as_float(c.y) * xc);
            atomicAdd(&acc[((d.x >> 16) & 63) * 33 + lb], __int_as_float(d.y) * xd);
        }
        for (; i < cnt; i += NSLOT) {
            const int2 a = stage[i];
            const float xa = xt[(size_t)(a.x & 0xFFFF) * BATCH + lb];
            atomicAdd(&acc[((a.x >> 16) & 63) * 33 + lb], __int_as_float(a.y) * xa);
        }
    }
    __syncthreads();

    // epilogue: out[b][m0+d] = acc[d][b] + bias[m0+d]; coalesced along d
    const int m0 = bkt * DPB;
    const int dd = threadIdx.x & 63;
    const int bq = threadIdx.x >> 6;   // 0..15
    #pragma unroll
    for (int k = 0; k < 2; ++k) {
        const int b = bq + (k << 4);
        const int m = m0 + dd;
        if (m < M) out[(size_t)b * M + m] = acc[dd * 33 + b] + bias[m];
    }
}

// ---- fallback (atomic) path ----
__global__ void k_init_out_t(const float* __restrict__ bias, float* __restrict__ out_t, int M) {
    const int i = blockIdx.x * blockDim.x + threadIdx.x;
    if (i < M * BATCH) out_t[i] = bias[i >> 5];
}

__global__ void k_scatter(const float* __restrict__ xt, const float* __restrict__ values,
                          const int* __restrict__ idx, float* __restrict__ out_t, int E) {
    const int t = blockIdx.x * blockDim.x + threadIdx.x;
    const int e = t >> 5;
    const int b = t & 31;
    if (e < E) {
        const int src = idx[e];
        const int dst = idx[E + e];
        const float contrib = values[e] * xt[(size_t)src * BATCH + b];
        atomicAdd(&out_t[(size_t)dst * BATCH + b], contrib);
    }
}

__global__ void k_transpose_out(const float* __restrict__ out_t, float* __restrict__ out, int M) {
    __shared__ float tile[32][33];
    const int m0 = blockIdx.x * 32;
    const int tx = threadIdx.x;
    const int ty = threadIdx.y;
    #pragma unroll
    for (int k = 0; k < 4; ++k) {
        const int m = m0 + ty + 8 * k;
        if (m < M) tile[ty + 8 * k][tx] = out_t[(size_t)m * BATCH + tx];
    }
    __syncthreads();
    #pragma unroll
    for (int k = 0; k < 4; ++k) {
        const int b = ty + 8 * k;
        const int m = m0 + tx;
        if (m < M) out[(size_t)b * M + m] = tile[tx][b];
    }
}

extern "C" void kernel_launch(void* const* d_in, const int* in_sizes, int n_in,
                              void* d_out, int out_size, void* d_ws, size_t ws_size,
                              hipStream_t stream) {
    const float* x      = (const float*)d_in[0];  // (B,N,1) fp32
    const float* values = (const float*)d_in[1];  // (E,)    fp32
    const float* bias   = (const float*)d_in[2];  // (M,1)   fp32
    const int*   idx    = (const int*)d_in[3];    // (2,E)   int32

    const int N = in_sizes[0] / BATCH;   // 50000
    const int E = in_sizes[3] / 2;       // 1600000
    const int M = in_sizes[2];           // 50000
    const int NB = (M + DPB - 1) / DPB;  // 782

    float* out = (float*)d_out;

    // ---- workspace carve (512B aligned) ----
    char* base = (char*)d_ws;
    size_t off = 0;
    auto carve = [&](size_t bytes) -> void* {
        void* r = base + off;
        off = (off + bytes + 511) & ~(size_t)511;
        return r;
    };
    float* xt       = (float*)carve((size_t)N * BATCH * sizeof(float));  // 6.4 MB
    size_t sv_mark  = off;
    int2*  sv       = (int2*)carve((size_t)E * sizeof(int2));            // 12.8 MB
    int*   gcount   = (int*)carve((size_t)NB * sizeof(int));
    int*   bbase    = (int*)carve((size_t)(NB + 1) * sizeof(int));
    int*   gcursor  = (int*)carve((size_t)NB * sizeof(int));
    const size_t csr_needed = off;
    // fallback out_t overlaps sv (never both live)
    float* out_t = (float*)((char*)d_ws + sv_mark);

    dim3 tblk(32, 8);
    k_transpose_x<<<(N + 31) / 32, tblk, 0, stream>>>(x, xt, N);

    const bool use_csr = (csr_needed <= ws_size) && (N <= 65536) && (NB <= 1024);
    if (use_csr) {
        const size_t hist_bytes = (size_t)NB * sizeof(int);
        k_zero_i32<<<(NB + 255) / 256, 256, 0, stream>>>(gcount, NB);
        k_bucket_count<<<512, 256, hist_bytes, stream>>>(idx, gcount, E, NB);
        k_scan_buckets<<<1, 1024, 0, stream>>>(gcount, bbase, gcursor, NB, E);
        const int chunk = BIN_TPB * BIN_EPT;
        k_bin<<<(E + chunk - 1) / chunk, BIN_TPB, 2 * hist_bytes, stream>>>(idx, values, gcursor, sv, E, NB);
        k_accum<<<NB, ACC_TPB, 0, stream>>>(sv, bbase, xt, bias, out, M);
    } else {
        // fallback: proven atomic path
        k_init_out_t<<<(M * BATCH + 255) / 256, 256, 0, stream>>>(bias, out_t, M);
        const long long total = (long long)E * BATCH;
        k_scatter<<<(int)((total + 255) / 256), 256, 0, stream>>>(xt, values, idx, out_t, E);
        k_transpose_out<<<(M + 31) / 32, tblk, 0, stream>>>(out_t, out, M);
    }
}

// Round 4
// 458.784 us; speedup vs baseline: 1.0093x; 1.0093x over previous
//
#include <hip/hip_runtime.h>

// SpMM: out[b,m] = bias[m] + sum_{e: dst[e]==m} values[e] * x[b, src[e]]
// B=32, N=M=50000, E=1600000.
// v5: round-3 post-mortem: v3 and v4 k_accum both 347us EXACTLY despite
// different occupancy/unroll -> compiler serialized the gather (VGPR=16
// cannot hold 4 in-flight loads; loads sunk into uses, ~1 outstanding/wave).
// Fix: explicit 8-deep software pipeline (stage-reads array -> 8 independent
// xt loads array -> 8 FMA+LDS-atomics), __launch_bounds__(1024,8) (VGPR cap
// 64, need ~40). Round-0 evidence says the memory system can do these same
// gathers in <<167us when enough loads are outstanding.

#define BATCH 32
#define DPB   64              // dsts per bucket -> NB = 782
#define ACC_TPB 1024
#define ACC_TILE 2560         // sv entries staged per round (20KB)
#define ACC_DEPTH 8           // independent gathers in flight per slot
#define BIN_TPB 1024
#define BIN_EPT 4             // chunk = 4096 edges

// ---- transpose x (B,N) -> xt (N,B), LDS tiled ----
__global__ void k_transpose_x(const float* __restrict__ x, float* __restrict__ xt, int N) {
    __shared__ float tile[32][33];
    const int n0 = blockIdx.x * 32;
    const int tx = threadIdx.x;   // 0..31
    const int ty = threadIdx.y;   // 0..7
    #pragma unroll
    for (int k = 0; k < 4; ++k) {
        const int b = ty + 8 * k;
        const int n = n0 + tx;
        tile[tx][b] = (n < N) ? x[(size_t)b * N + n] : 0.0f;
    }
    __syncthreads();
    #pragma unroll
    for (int k = 0; k < 4; ++k) {
        const int n = n0 + ty + 8 * k;
        if (n < N) xt[(size_t)n * BATCH + tx] = tile[ty + 8 * k][tx];
    }
}

__global__ void k_zero_i32(int* __restrict__ p, int n) {
    const int i = blockIdx.x * blockDim.x + threadIdx.x;
    if (i < n) p[i] = 0;
}

// ---- per-bucket global histogram via LDS staging ----
__global__ __launch_bounds__(256) void k_bucket_count(const int* __restrict__ idx,
                                                      int* __restrict__ gcount,
                                                      int E, int NB) {
    extern __shared__ int hist[];
    for (int i = threadIdx.x; i < NB; i += blockDim.x) hist[i] = 0;
    __syncthreads();
    const int stride = gridDim.x * blockDim.x;
    for (int e = blockIdx.x * blockDim.x + threadIdx.x; e < E; e += stride) {
        atomicAdd(&hist[idx[E + e] / DPB], 1);
    }
    __syncthreads();
    for (int i = threadIdx.x; i < NB; i += blockDim.x) {
        if (hist[i]) atomicAdd(&gcount[i], hist[i]);
    }
}

// ---- single-wg exclusive scan of bucket counts (NB <= 1024) ----
__global__ __launch_bounds__(1024) void k_scan_buckets(const int* __restrict__ gcount,
                                                       int* __restrict__ bucket_base,
                                                       int* __restrict__ gcursor,
                                                       int NB, int E) {
    __shared__ int s[1024];
    const int tid = threadIdx.x;
    const int v = (tid < NB) ? gcount[tid] : 0;
    s[tid] = v;
    __syncthreads();
    for (int off = 1; off < 1024; off <<= 1) {
        const int t = (tid >= off) ? s[tid - off] : 0;
        __syncthreads();
        s[tid] += t;
        __syncthreads();
    }
    if (tid < NB) {
        const int excl = s[tid] - v;
        bucket_base[tid] = excl;
        gcursor[tid] = excl;
    }
    if (tid == 0) bucket_base[NB] = E;
}

// ---- bin edges into bucket-contiguous segments, packed (src|dl<<16, val) ----
__global__ __launch_bounds__(BIN_TPB) void k_bin(const int* __restrict__ idx,
                                                 const float* __restrict__ values,
                                                 int* __restrict__ gcursor,
                                                 int2* __restrict__ sv,
                                                 int E, int NB) {
    extern __shared__ int lds[];
    int* hist = lds;          // [NB] counts, then reused as local cursor
    int* base = lds + NB;     // [NB] this chunk's global segment base
    for (int i = threadIdx.x; i < NB; i += BIN_TPB) hist[i] = 0;
    __syncthreads();

    const int c0 = blockIdx.x * (BIN_TPB * BIN_EPT);
    int d[BIN_EPT];
    #pragma unroll
    for (int i = 0; i < BIN_EPT; ++i) {
        const int e = c0 + threadIdx.x + i * BIN_TPB;
        d[i] = (e < E) ? idx[E + e] : -1;
        if (d[i] >= 0) atomicAdd(&hist[d[i] / DPB], 1);
    }
    __syncthreads();
    // reserve contiguous global segments, reset local cursors
    for (int i = threadIdx.x; i < NB; i += BIN_TPB) {
        const int c = hist[i];
        base[i] = c ? atomicAdd(&gcursor[i], c) : 0;
        hist[i] = 0;
    }
    __syncthreads();
    #pragma unroll
    for (int i = 0; i < BIN_EPT; ++i) {
        if (d[i] >= 0) {
            const int e = c0 + threadIdx.x + i * BIN_TPB;
            const int bkt = d[i] / DPB;
            const int off = atomicAdd(&hist[bkt], 1);
            const int packed = (idx[e] & 0xFFFF) | ((d[i] % DPB) << 16);
            sv[base[bkt] + off] = make_int2(packed, __float_as_int(values[e]));
        }
    }
}

// ---- one block per bucket: explicit 8-deep pipelined gather + LDS accumulate ----
__global__ __launch_bounds__(ACC_TPB, 8) void k_accum(const int2* __restrict__ sv,
                                                      const int* __restrict__ bucket_base,
                                                      const float* __restrict__ xt,
                                                      const float* __restrict__ bias,
                                                      float* __restrict__ out, int M) {
    __shared__ float acc[DPB * 33];      // [dl][b] padded: bank = (dl+b)%32
    __shared__ int2  stage[ACC_TILE];    // staged sv segment
    for (int i = threadIdx.x; i < DPB * 33; i += ACC_TPB) acc[i] = 0.0f;

    const int bkt = blockIdx.x;
    const int beg = bucket_base[bkt];
    const int end = bucket_base[bkt + 1];

    const int slot  = threadIdx.x >> 5;      // 0..31 (half-wave id)
    const int lb    = threadIdx.x & 31;      // batch lane
    const int NSLOT = ACC_TPB / 32;          // 32

    for (int t0 = beg; t0 < end; t0 += ACC_TILE) {
        const int cnt = min(ACC_TILE, end - t0);
        __syncthreads();   // acc init done (1st iter) / prev tile consumed
        for (int i = threadIdx.x; i < cnt; i += ACC_TPB) stage[i] = sv[t0 + i];
        __syncthreads();

        int i = slot;
        // explicit pipeline: read 8 stage entries, issue 8 independent global
        // loads, only then touch LDS atomics. Arrays are fully unrolled so
        // every index is compile-time constant (stays in VGPRs).
        for (; i + (ACC_DEPTH - 1) * NSLOT < cnt; i += ACC_DEPTH * NSLOT) {
            int2  e[ACC_DEPTH];
            float xv[ACC_DEPTH];
            #pragma unroll
            for (int k = 0; k < ACC_DEPTH; ++k) e[k] = stage[i + k * NSLOT];
            #pragma unroll
            for (int k = 0; k < ACC_DEPTH; ++k)
                xv[k] = xt[(size_t)(e[k].x & 0xFFFF) * BATCH + lb];
            #pragma unroll
            for (int k = 0; k < ACC_DEPTH; ++k)
                atomicAdd(&acc[((e[k].x >> 16) & 63) * 33 + lb],
                          __int_as_float(e[k].y) * xv[k]);
        }
        for (; i < cnt; i += NSLOT) {
            const int2 a = stage[i];
            const float xa = xt[(size_t)(a.x & 0xFFFF) * BATCH + lb];
            atomicAdd(&acc[((a.x >> 16) & 63) * 33 + lb], __int_as_float(a.y) * xa);
        }
    }
    __syncthreads();

    // epilogue: out[b][m0+d] = acc[d][b] + bias[m0+d]; coalesced along d
    const int m0 = bkt * DPB;
    const int dd = threadIdx.x & 63;
    const int bq = threadIdx.x >> 6;   // 0..15
    #pragma unroll
    for (int k = 0; k < 2; ++k) {
        const int b = bq + (k << 4);
        const int m = m0 + dd;
        if (m < M) out[(size_t)b * M + m] = acc[dd * 33 + b] + bias[m];
    }
}

// ---- fallback (atomic) path ----
__global__ void k_init_out_t(const float* __restrict__ bias, float* __restrict__ out_t, int M) {
    const int i = blockIdx.x * blockDim.x + threadIdx.x;
    if (i < M * BATCH) out_t[i] = bias[i >> 5];
}

__global__ void k_scatter(const float* __restrict__ xt, const float* __restrict__ values,
                          const int* __restrict__ idx, float* __restrict__ out_t, int E) {
    const int t = blockIdx.x * blockDim.x + threadIdx.x;
    const int e = t >> 5;
    const int b = t & 31;
    if (e < E) {
        const int src = idx[e];
        const int dst = idx[E + e];
        const float contrib = values[e] * xt[(size_t)src * BATCH + b];
        atomicAdd(&out_t[(size_t)dst * BATCH + b], contrib);
    }
}

__global__ void k_transpose_out(const float* __restrict__ out_t, float* __restrict__ out, int M) {
    __shared__ float tile[32][33];
    const int m0 = blockIdx.x * 32;
    const int tx = threadIdx.x;
    const int ty = threadIdx.y;
    #pragma unroll
    for (int k = 0; k < 4; ++k) {
        const int m = m0 + ty + 8 * k;
        if (m < M) tile[ty + 8 * k][tx] = out_t[(size_t)m * BATCH + tx];
    }
    __syncthreads();
    #pragma unroll
    for (int k = 0; k < 4; ++k) {
        const int b = ty + 8 * k;
        const int m = m0 + tx;
        if (m < M) out[(size_t)b * M + m] = tile[tx][b];
    }
}

extern "C" void kernel_launch(void* const* d_in, const int* in_sizes, int n_in,
                              void* d_out, int out_size, void* d_ws, size_t ws_size,
                              hipStream_t stream) {
    const float* x      = (const float*)d_in[0];  // (B,N,1) fp32
    const float* values = (const float*)d_in[1];  // (E,)    fp32
    const float* bias   = (const float*)d_in[2];  // (M,1)   fp32
    const int*   idx    = (const int*)d_in[3];    // (2,E)   int32

    const int N = in_sizes[0] / BATCH;   // 50000
    const int E = in_sizes[3] / 2;       // 1600000
    const int M = in_sizes[2];           // 50000
    const int NB = (M + DPB - 1) / DPB;  // 782

    float* out = (float*)d_out;

    // ---- workspace carve (512B aligned) ----
    char* base = (char*)d_ws;
    size_t off = 0;
    auto carve = [&](size_t bytes) -> void* {
        void* r = base + off;
        off = (off + bytes + 511) & ~(size_t)511;
        return r;
    };
    float* xt       = (float*)carve((size_t)N * BATCH * sizeof(float));  // 6.4 MB
    size_t sv_mark  = off;
    int2*  sv       = (int2*)carve((size_t)E * sizeof(int2));            // 12.8 MB
    int*   gcount   = (int*)carve((size_t)NB * sizeof(int));
    int*   bbase    = (int*)carve((size_t)(NB + 1) * sizeof(int));
    int*   gcursor  = (int*)carve((size_t)NB * sizeof(int));
    const size_t csr_needed = off;
    // fallback out_t overlaps sv (never both live)
    float* out_t = (float*)((char*)d_ws + sv_mark);

    dim3 tblk(32, 8);
    k_transpose_x<<<(N + 31) / 32, tblk, 0, stream>>>(x, xt, N);

    const bool use_csr = (csr_needed <= ws_size) && (N <= 65536) && (NB <= 1024);
    if (use_csr) {
        const size_t hist_bytes = (size_t)NB * sizeof(int);
        k_zero_i32<<<(NB + 255) / 256, 256, 0, stream>>>(gcount, NB);
        k_bucket_count<<<512, 256, hist_bytes, stream>>>(idx, gcount, E, NB);
        k_scan_buckets<<<1, 1024, 0, stream>>>(gcount, bbase, gcursor, NB, E);
        const int chunk = BIN_TPB * BIN_EPT;
        k_bin<<<(E + chunk - 1) / chunk, BIN_TPB, 2 * hist_bytes, stream>>>(idx, values, gcursor, sv, E, NB);
        k_accum<<<NB, ACC_TPB, 0, stream>>>(sv, bbase, xt, bias, out, M);
    } else {
        // fallback: proven atomic path
        k_init_out_t<<<(M * BATCH + 255) / 256, 256, 0, stream>>>(bias, out_t, M);
        const long long total = (long long)E * BATCH;
        k_scatter<<<(int)((total + 255) / 256), 256, 0, stream>>>(xt, values, idx, out_t, E);
        k_transpose_out<<<(M + 31) / 32, tblk, 0, stream>>>(out_t, out, M);
    }
}